// Round 7
// baseline (2718.089 us; speedup 1.0000x reference)
//
#include <hip/hip_runtime.h>
#include <hip/hip_cooperative_groups.h>
#include <math.h>

namespace cg = cooperative_groups;

#define T_ 64
#define M_ 256
#define K_ 6
#define B_ 256
#define H_ 256
#define L_ 128
#define V_ 780
#define E_ (T_*M_)       // 16384
#define ZD 383           // H+L-1
#define UD 638           // 2H+L-2
#define KP 384           // ZD padded for MFMA
#define VP 832           // V padded to 13*64

typedef unsigned short ushort_t;
typedef __attribute__((ext_vector_type(8))) short bf16x8v;
typedef __attribute__((ext_vector_type(4))) float f32x4v;

// ---------------- helpers ----------------

__device__ __forceinline__ float blk_sum(float v, float* red) {
    int j = threadIdx.x;
    #pragma unroll
    for (int o = 32; o > 0; o >>= 1) v += __shfl_down(v, o, 64);
    __syncthreads();
    if ((j & 63) == 0) red[j >> 6] = v;
    __syncthreads();
    return red[0] + red[1] + red[2] + red[3];
}

__device__ __forceinline__ float wave_sum(float v) {
    #pragma unroll
    for (int o = 32; o > 0; o >>= 1) v += __shfl_xor(v, o, 64);
    return v;
}

__device__ __forceinline__ void wave_maxarg(float& v, int& i) {
    #pragma unroll
    for (int o = 32; o > 0; o >>= 1) {
        float vo = __shfl_xor(v, o, 64);
        int   io = __shfl_xor(i, o, 64);
        if (vo > v || (vo == v && io < i)) { v = vo; i = io; }
    }
}

__device__ __forceinline__ ushort_t f2bf(float x) {
    union { float f; unsigned int u; } a; a.f = x;
    unsigned int r = a.u + 0x7fffu + ((a.u >> 16) & 1u);
    return (ushort_t)(r >> 16);
}

// ---------------- init ----------------

__global__ __launch_bounds__(256) void init_k(float* hbuf) {
    int idx = blockIdx.x * 256 + threadIdx.x;
    if (idx < (E_ + 1) * H_) hbuf[idx] = ((idx & (H_ - 1)) == 0) ? 1.f : 0.f;
}

__global__ __launch_bounds__(256) void transpose_k(const float* __restrict__ W0,
                                                   const float* __restrict__ W1,
                                                   float* __restrict__ W0T,
                                                   float* __restrict__ W1T) {
    int idx = blockIdx.x * 256 + threadIdx.x;
    if (idx < H_ * H_) {
        int i = idx >> 8, j = idx & 255;
        W0T[idx] = W0[j * H_ + i];
    }
    int idx2 = idx - H_ * H_;
    if (idx2 >= 0 && idx2 < (2 * H_ - 1) * H_) {
        int i = idx2 >> 8, j = idx2 & 255;
        W1T[idx2] = W1[j * (2 * H_ - 1) + i];
    }
}

// convert wcls -> bf16 padded [VP][KP]
__global__ __launch_bounds__(256) void wconv(const float* __restrict__ wcls,
                                             ushort_t* __restrict__ Wb) {
    int idx = blockIdx.x * 256 + threadIdx.x;
    if (idx >= VP * KP) return;
    int v = idx / KP, k = idx - v * KP;
    float val = (v < V_ && k < ZD) ? wcls[(size_t)v * ZD + k] : 0.f;
    Wb[idx] = f2bf(val);
}

// ---------------- persistent scan: all 64 steps in one cooperative kernel ----------------
// 256 blocks (1 per m, co-resident via cooperative launch) x 512 threads
// (8 waves, 2/SIMD). W0T slice cached in REGISTERS (float4 w0r[32] per
// thread, loaded once, reused for all 64 steps). W1T streamed from L2 each
// step. grid.sync() between steps replaces the 64 kernel launches.
// Arithmetic order identical to scan4 (passed, absmax 8.0).

__global__ __launch_bounds__(512, 2) void scan_persist(float* __restrict__ hbuf,
        const float* __restrict__ W0T, const float* __restrict__ b0, const float* __restrict__ s0p,
        const float* __restrict__ W1T, const float* __restrict__ b1, const float* __restrict__ s1p,
        const float* __restrict__ emb, const int* __restrict__ wid,
        const int* __restrict__ nhi, const float* __restrict__ nhw) {
    cg::grid_group grid = cg::this_grid();
    int tid = threadIdx.x;
    int w = tid >> 6, l = tid & 63;      // wave 0..7
    int j = tid & 255, half = tid >> 8;  // column, thread-half
    int m = blockIdx.x;

    __shared__ __align__(16) float hn[K_][H_];          // 6 KB
    __shared__ __align__(16) float pw0[8][K_][H_];      // 48 KB
    __shared__ __align__(16) float zz[512];             // 2 KB (511 used)
    __shared__ __align__(16) float py2[8][H_];          // 8 KB
    __shared__ __align__(16) float redk[4][8];
    __shared__ float y0s[K_];
    __shared__ float sca[1];

    // ---- persistent register cache of W0T: wave w's rows w*32..w*32+31,
    //      lane l's cols 4l..4l+3 ----
    float4 w0r[32];
    {
        int i0 = w * 32;
        #pragma unroll
        for (int i = 0; i < 32; i++)
            w0r[i] = *(const float4*)(W0T + (size_t)(i0 + i) * H_ + 4 * l);
    }
    float es0 = expf(s0p[0]);
    float es1 = expf(s1p[0]);
    float bj  = b0[j];
    float b1j = b1[j];

    for (int t = 0; t < T_; t++) {
        const int*   ip = nhi + (t * M_ + m) * K_;
        const float* wp = nhw + (t * M_ + m) * K_;

        // stage neighbor rows: half 0 -> k 0..2, half 1 -> k 3..5
        #pragma unroll
        for (int k3 = 0; k3 < 3; k3++) {
            int k = half * 3 + k3;
            hn[k][j] = hbuf[(size_t)ip[k] * H_ + j];
        }
        __syncthreads();

        // ---- W0 GEMM from registers: y[k][j] = sum_i hn[k][i] * W0T[i][j] ----
        float4 a0[K_];
        #pragma unroll
        for (int k = 0; k < K_; k++) a0[k] = make_float4(0.f, 0.f, 0.f, 0.f);
        {
            int i0 = w * 32;
            #pragma unroll
            for (int i = 0; i < 32; i++) {
                float4 wv = w0r[i];
                #pragma unroll
                for (int k = 0; k < K_; k++) {
                    float h = hn[k][i0 + i];
                    a0[k].x += h * wv.x; a0[k].y += h * wv.y;
                    a0[k].z += h * wv.z; a0[k].w += h * wv.w;
                }
            }
        }
        #pragma unroll
        for (int k = 0; k < K_; k++)
            *(float4*)&pw0[w][k][4 * l] = a0[k];
        __syncthreads();

        // reduce partials: thread owns col j (replicated across halves)
        float y[K_];
        #pragma unroll
        for (int k = 0; k < K_; k++) {
            float s = pw0[0][k][j];
            #pragma unroll
            for (int ww = 1; ww < 8; ww++) s += pw0[ww][k][j];
            y[k] = s + bj;
        }

        // batched ssq reductions over j (waves 0..3 only; same tree as scan4)
        if (tid < 256) {
            int w4 = tid >> 6;
            #pragma unroll
            for (int k = 0; k < K_; k++) {
                float c = (tid == 0) ? 0.f : y[k] * y[k];
                c = wave_sum(c);
                if (l == 0) redk[w4][k] = c;
            }
            if (tid == 0) {
                #pragma unroll
                for (int k = 0; k < K_; k++) y0s[k] = y[k];
            }
        }
        __syncthreads();

        float ave = 0.f, wsum = 0.f;
        #pragma unroll
        for (int k = 0; k < K_; k++) {
            float ssq = redk[0][k] + redk[1][k] + redk[2][k] + redk[3][k];
            float tm  = es0 / (1.f + expf(-y0s[k])) + 1.1f;
            float sc  = sqrtf((tm * tm - 1.f) / fmaxf(ssq, 1e-8f));
            float h1v = (j == 0) ? tm : y[k] * sc;
            float wk  = wp[k];
            ave += wk * h1v; wsum += wk;
        }
        ave /= fmaxf(wsum, 1e-8f);

        if (tid < 256) {
            int w4 = tid >> 6;
            float innl = (tid == 0) ? -ave * ave : ave * ave;
            innl = wave_sum(innl);
            if (l == 0) redk[w4][6] = innl;
        }
        __syncthreads();
        float inner = redk[0][6] + redk[1][6] + redk[2][6] + redk[3][6];
        float h1m = ave / sqrtf(fmaxf(-inner, 1e-8f));

        if (tid < 256) {
            int wde = wid[t * M_ + m];
            float cx = emb[(size_t)wde * H_ + j];
            if (j == 0) {
                zz[0] = sqrtf(fmaxf(cx * cx + h1m * h1m - 1.f, 1e-8f));
            } else {
                zz[j] = cx;
                zz[255 + j] = h1m;
            }
        }
        __syncthreads();

        // ---- W1 GEMM (streamed): y2[j] = sum_i zz[i] * W1T[i][j] ----
        float a1[4] = {0.f, 0.f, 0.f, 0.f};
        {
            int i0 = w * 64;
            int i1 = (i0 + 64 < 2 * H_ - 1) ? (i0 + 64) : (2 * H_ - 1);
            #pragma unroll 4
            for (int i = i0; i < i1; i++) {
                float4 wv = *(const float4*)(W1T + (size_t)i * H_ + 4 * l);
                float z = zz[i];
                a1[0] += z * wv.x; a1[1] += z * wv.y;
                a1[2] += z * wv.z; a1[3] += z * wv.w;
            }
        }
        *(float4*)&py2[w][4 * l] = make_float4(a1[0], a1[1], a1[2], a1[3]);
        __syncthreads();

        if (tid < 256) {
            int w4 = tid >> 6;
            float y2 = py2[0][j];
            #pragma unroll
            for (int ww = 1; ww < 8; ww++) y2 += py2[ww][j];
            y2 += b1j;
            float c2 = (tid == 0) ? 0.f : y2 * y2;
            c2 = wave_sum(c2);
            if (l == 0) redk[w4][7] = c2;
            if (tid == 0) sca[0] = y2;
            __syncthreads();
            float ssq2 = redk[0][7] + redk[1][7] + redk[2][7] + redk[3][7];
            float tm2  = es1 / (1.f + expf(-sca[0])) + 1.1f;
            float sc2  = sqrtf((tm2 * tm2 - 1.f) / fmaxf(ssq2, 1e-8f));
            float nh   = (tid == 0) ? tm2 : y2 * sc2;
            hbuf[(size_t)(t * M_ + m) * H_ + j] = nh;
        } else {
            __syncthreads();   // matched barrier
        }

        if (t < T_ - 1) grid.sync();   // cross-XCD visibility of hbuf writes
    }
}

// ---------------- build Zb (bf16, K padded) with sign-folded z0 ----------------

__global__ __launch_bounds__(256) void zbuild2(const float* __restrict__ hbuf,
                                               const float* __restrict__ xtv,
                                               const int* __restrict__ bidx,
                                               ushort_t* __restrict__ Zb) {
    int e = blockIdx.x, j = threadIdx.x;
    int bi = bidx[e];
    ushort_t* zr = Zb + (size_t)e * KP;
    if (j == 0) {
        float nh0 = hbuf[(size_t)e * H_];
        float c0  = xtv[(size_t)bi * L_];
        float z0  = sqrtf(fmaxf(nh0 * nh0 + c0 * c0 - 1.f, 1e-8f));
        zr[0] = f2bf(-z0);   // fold the centroid's -x0*cls0 sign here
    } else {
        zr[j] = f2bf(hbuf[(size_t)e * H_ + j]);
    }
    if (j < 128) {
        int c = 256 + j;                       // 256..383
        float v = (c <= 382) ? xtv[(size_t)bi * L_ + (c - 255)] : 0.f;
        zr[c] = f2bf(v);
    }
}

// ---------------- msg scores GEMM (MFMA bf16): SC = 2 + 2*(Z @ wcls^T) + wbias ----------------

__global__ __launch_bounds__(256) void gemm_mfma(const ushort_t* __restrict__ Zb,
                                                 const ushort_t* __restrict__ Wb,
                                                 const float* __restrict__ wbias,
                                                 float* __restrict__ SC) {
    __shared__ __align__(16) ushort_t As[64][40];
    __shared__ __align__(16) ushort_t Bs[64][40];
    int tid = threadIdx.x;
    int w = tid >> 6, l = tid & 63;
    int m0 = blockIdx.x * 64;
    int n0 = blockIdx.y * 64;
    int r16 = l & 15, q8 = (l >> 4) * 8;

    int srow = tid >> 2;            // 0..63
    int schunk = (tid & 3) * 8;     // 0,8,16,24

    f32x4v acc[4];
    #pragma unroll
    for (int mt = 0; mt < 4; mt++) acc[mt] = (f32x4v){0.f, 0.f, 0.f, 0.f};

    for (int ks = 0; ks < KP / 32; ks++) {
        int k0 = ks * 32;
        __syncthreads();
        *(uint4*)&As[srow][schunk] = *(const uint4*)(Zb + (size_t)(m0 + srow) * KP + k0 + schunk);
        *(uint4*)&Bs[srow][schunk] = *(const uint4*)(Wb + (size_t)(n0 + srow) * KP + k0 + schunk);
        __syncthreads();

        bf16x8v bfr = *(const bf16x8v*)(&Bs[w * 16 + r16][q8]);
        #pragma unroll
        for (int mt = 0; mt < 4; mt++) {
            bf16x8v afr = *(const bf16x8v*)(&As[mt * 16 + r16][q8]);
            acc[mt] = __builtin_amdgcn_mfma_f32_16x16x32_bf16(afr, bfr, acc[mt], 0, 0, 0);
        }
    }

    int n = n0 + w * 16 + r16;
    if (n < V_) {
        float bias = wbias[n];
        #pragma unroll
        for (int mt = 0; mt < 4; mt++) {
            #pragma unroll
            for (int r = 0; r < 4; r++) {
                int mrow = m0 + mt * 16 + (l >> 4) * 4 + r;
                SC[(size_t)mrow * V_ + n] = 2.f + 2.f * acc[mt][r] + bias;
            }
        }
    }
}

// ---------------- msg CE (masked by direction), wave-per-row, no atomics ----------------

__global__ __launch_bounds__(256) void msg_ce2(const float* __restrict__ SC,
                                               const int* __restrict__ pt,
                                               const int* __restrict__ dir,
                                               float* __restrict__ part) {
    int w = threadIdx.x >> 6, l = threadIdx.x & 63;
    int wg = blockIdx.x * 4 + w;     // 0..1023
    float lloss = 0.f, lhit = 0.f, lpm = 0.f;
    for (int i = 0; i < 16; i++) {
        int e = wg * 16 + i;
        const float* s = SC + (size_t)e * V_;
        float sv[13];
        float mx = -1e30f; int mi = 0;
        #pragma unroll
        for (int ii = 0; ii < 13; ii++) {
            int v = l + ii * 64;
            float x = (v < V_) ? s[v] : -1e30f;
            sv[ii] = x;
            if (x > mx) { mx = x; mi = v; }
        }
        wave_maxarg(mx, mi);
        float se = 0.f;
        #pragma unroll
        for (int ii = 0; ii < 13; ii++) se += expf(sv[ii] - mx);
        se = wave_sum(se);
        if (l == 0) {
            int tgt = pt[e];
            float lse = mx + logf(se);
            float pm = (float)dir[e];
            lloss += pm * (lse - s[tgt]);
            lhit  += pm * ((mi == tgt) ? 1.f : 0.f);
            lpm   += pm;
        }
    }
    __shared__ float red[4][3];
    if (l == 0) { red[w][0] = lloss; red[w][1] = lhit; red[w][2] = lpm; }
    __syncthreads();
    if (threadIdx.x == 0) {
        float* pr = part + (size_t)blockIdx.x * 8;
        pr[0] = red[0][0] + red[1][0] + red[2][0] + red[3][0];
        pr[1] = red[0][1] + red[1][1] + red[2][1] + red[3][1];
        pr[2] = red[0][2] + red[1][2] + red[2][2] + red[3][2];
        pr[3] = 0.f; pr[4] = 0.f;
    }
}

// ---------------- stop head per message, wave-per-row, no atomics ----------------

__global__ __launch_bounds__(256) void stop_e2(const float* __restrict__ hbuf,
        const float* __restrict__ emb, const float* __restrict__ xtv,
        const int* __restrict__ wid, const int* __restrict__ noi, const float* __restrict__ now_w,
        const int* __restrict__ bidx, const int* __restrict__ dir,
        const float* __restrict__ ucls, const float* __restrict__ ubias,
        float* __restrict__ part) {
    int w = threadIdx.x >> 6, l = threadIdx.x & 63;
    int wg = blockIdx.x * 4 + w;

    float ua0[4], ub0[4], ua1[4], ub1[4], uc0[2], uc1[2];
    #pragma unroll
    for (int s = 0; s < 4; s++) {
        int j = s * 64 + l;
        ua0[s] = ucls[j];        ub0[s] = ucls[255 + j];
        ua1[s] = ucls[UD + j];   ub1[s] = ucls[UD + 255 + j];
    }
    #pragma unroll
    for (int s = 0; s < 2; s++) {
        int j = s * 64 + l;
        uc0[s] = ucls[510 + j];  uc1[s] = ucls[UD + 510 + j];
    }
    float u00 = ucls[0], u10 = ucls[UD];
    float ubs0 = ubias[0], ubs1 = ubias[1];

    float lloss = 0.f, lhit = 0.f;
    for (int i = 0; i < 16; i++) {
        int e = wg * 16 + i;
        const int*   ip = noi + e * K_;
        const float* wp = now_w + e * K_;
        float ave[4] = {0.f, 0.f, 0.f, 0.f};
        float wsum = 0.f;
        #pragma unroll
        for (int k = 0; k < K_; k++) {
            int id = ip[k]; float wt = wp[k];
            wsum += wt;
            const float* hr = hbuf + (size_t)id * H_;
            #pragma unroll
            for (int s = 0; s < 4; s++) ave[s] += wt * hr[s * 64 + l];
        }
        float inv = 1.f / fmaxf(wsum, 1e-8f);
        float innl = 0.f;
        #pragma unroll
        for (int s = 0; s < 4; s++) { ave[s] *= inv; innl += ave[s] * ave[s]; }
        if (l == 0) innl -= 2.f * ave[0] * ave[0];
        float inner = wave_sum(innl);
        float cs = 1.f / sqrtf(fmaxf(-inner, 1e-8f));

        int we = wid[e], bi = bidx[e];
        const float* er = emb + (size_t)we * H_;
        const float* cr = xtv + (size_t)bi * L_;

        float p0 = 0.f, p1 = 0.f;
        #pragma unroll
        for (int s = 0; s < 4; s++) {
            float cx = er[s * 64 + l];
            float co = ave[s] * cs;
            if (s == 0 && l == 0) {
                float ctx0 = cr[0];
                float t1sq = fmaxf(cx * cx + co * co - 1.f, 1e-8f);
                float sh0 = sqrtf(fmaxf(t1sq + ctx0 * ctx0 - 1.f, 1e-8f));
                p0 += -sh0 * u00; p1 += -sh0 * u10;
            } else {
                p0 += cx * ua0[s] + co * ub0[s];
                p1 += cx * ua1[s] + co * ub1[s];
            }
            if (s < 2) {
                int j = s * 64 + l;
                if (j >= 1) {
                    float ctx = cr[j];
                    p0 += ctx * uc0[s]; p1 += ctx * uc1[s];
                }
            }
        }
        p0 = wave_sum(p0); p1 = wave_sum(p1);
        if (l == 0) {
            float sc0 = 2.f + 2.f * p0 + ubs0;
            float sc1 = 2.f + 2.f * p1 + ubs1;
            int tgt = dir[e];
            float m = fmaxf(sc0, sc1);
            float lse = m + logf(expf(sc0 - m) + expf(sc1 - m));
            lloss += lse - ((tgt == 0) ? sc0 : sc1);
            int am = (sc1 > sc0) ? 1 : 0;
            lhit += (am == tgt) ? 1.f : 0.f;
        }
    }
    __shared__ float red[4][2];
    if (l == 0) { red[w][0] = lloss; red[w][1] = lhit; }
    __syncthreads();
    if (threadIdx.x == 0) {
        float* pr = part + (size_t)(256 + blockIdx.x) * 8;
        pr[0] = 0.f; pr[1] = 0.f; pr[2] = 0.f;
        pr[3] = red[0][0] + red[1][0] + red[2][0] + red[3][0];
        pr[4] = red[0][1] + red[1][1] + red[2][1] + red[3][1];
    }
}

// ---------------- root: stop head + pred head ----------------

__global__ __launch_bounds__(256) void root_k(const float* __restrict__ hbuf,
        const float* __restrict__ emb, const float* __restrict__ xtv,
        const int* __restrict__ rwid, const int* __restrict__ roi, const float* __restrict__ row_w,
        const float* __restrict__ wcls, const float* __restrict__ wbias,
        const float* __restrict__ ucls, const float* __restrict__ ubias,
        float* __restrict__ part) {
    int b = blockIdx.x, j = threadIdx.x;
    __shared__ float red[256];
    __shared__ int   redi[256];
    __shared__ float shs[4];
    __shared__ float ctxs[L_];
    __shared__ float sc[V_];
    float* pr = part + (size_t)(512 + b) * 8;

    const int*   ip = roi + b * K_;
    const float* wp = row_w + b * K_;
    float ave = 0.f, wsum = 0.f;
    #pragma unroll
    for (int k = 0; k < K_; k++) {
        int id = ip[k]; float w = wp[k];
        ave += w * hbuf[(size_t)id * H_ + j];
        wsum += w;
    }
    ave /= fmaxf(wsum, 1e-8f);
    float inner = blk_sum((j == 0) ? -ave * ave : ave * ave, red);
    float ro = ave / sqrtf(fmaxf(-inner, 1e-8f));

    int   rw = rwid[b];
    float er = emb[(size_t)rw * H_ + j];
    float ctxj = (j < L_) ? xtv[(size_t)b * L_ + j] : 0.f;
    if (j == 0) { shs[0] = er; shs[1] = ro; shs[2] = ctxj; }
    if (j < L_) ctxs[j] = ctxj;
    __syncthreads();
    float t1sq = fmaxf(shs[0] * shs[0] + shs[1] * shs[1] - 1.f, 1e-8f);
    float sh0  = sqrtf(fmaxf(t1sq + shs[2] * shs[2] - 1.f, 1e-8f));

    float p0, p1;
    if (j >= 1) {
        p0 = er * ucls[j] + ro * ucls[255 + j];
        p1 = er * ucls[UD + j] + ro * ucls[UD + 255 + j];
        if (j < L_) { p0 += ctxj * ucls[510 + j]; p1 += ctxj * ucls[UD + 510 + j]; }
    } else {
        p0 = -sh0 * ucls[0];
        p1 = -sh0 * ucls[UD];
    }
    float s0 = 2.f + 2.f * blk_sum(p0, red) + ubias[0];
    float s1 = 2.f + 2.f * blk_sum(p1, red) + ubias[1];
    if (j == 0) {
        float m = fmaxf(s0, s1);
        float lse = m + logf(expf(s0 - m) + expf(s1 - m));
        int am = (s1 > s0) ? 1 : 0;
        pr[3] = lse - s0;
        pr[4] = (am == 0) ? 1.f : 0.f;
    }

    float c0 = shs[2];
    float z0 = sqrtf(fmaxf(c0 * c0, 1e-8f));
    __syncthreads();
    for (int v = j; v < V_; v += 256) {
        const float* wv = wcls + (size_t)v * ZD;
        float d = -z0 * wv[0];
        for (int i = 1; i < L_; i++) d += ctxs[i] * wv[255 + i];
        sc[v] = 2.f + 2.f * d + wbias[v];
    }
    __syncthreads();
    float mx = -1e30f; int mi = 0;
    for (int v = j; v < V_; v += 256) { float x = sc[v]; if (x > mx) { mx = x; mi = v; } }
    red[j] = mx; redi[j] = mi;
    __syncthreads();
    for (int o = 128; o > 0; o >>= 1) {
        if (j < o) {
            float xo = red[j + o]; int io = redi[j + o];
            if (xo > red[j] || (xo == red[j] && io < redi[j])) { red[j] = xo; redi[j] = io; }
        }
        __syncthreads();
    }
    float gm = red[0]; int ga = redi[0];
    __syncthreads();
    float se = 0.f;
    for (int v = j; v < V_; v += 256) se += expf(sc[v] - gm);
    red[j] = se;
    __syncthreads();
    for (int o = 128; o > 0; o >>= 1) { if (j < o) red[j] += red[j + o]; __syncthreads(); }
    if (j == 0) {
        float lse = gm + logf(red[0]);
        pr[0] = lse - sc[rw];
        pr[1] = (ga == rw) ? 1.f : 0.f;
        pr[2] = 0.f;
    }
}

// ---------------- finalize ----------------

__global__ __launch_bounds__(256) void finalize2(const float* __restrict__ part,
                                                 float* __restrict__ out) {
    int j = threadIdx.x;
    __shared__ float red[256][5];
    #pragma unroll
    for (int c = 0; c < 5; c++)
        red[j][c] = part[(size_t)j * 8 + c] + part[(size_t)(j + 256) * 8 + c]
                  + part[(size_t)(j + 512) * 8 + c];
    __syncthreads();
    for (int o = 128; o > 0; o >>= 1) {
        if (j < o) {
            #pragma unroll
            for (int c = 0; c < 5; c++) red[j][c] += red[j + o][c];
        }
        __syncthreads();
    }
    if (j == 0) {
        out[0] = red[0][0] / (float)B_;
        out[1] = red[0][3] / (float)B_;
        out[2] = red[0][1] / ((float)B_ + red[0][2]);
        out[3] = red[0][4] / (float)(E_ + B_);
    }
}

// ---------------- launch ----------------

extern "C" void kernel_launch(void* const* d_in, const int* in_sizes, int n_in,
                              void* d_out, int out_size, void* d_ws, size_t ws_size,
                              hipStream_t stream) {
    const int*   wid   = (const int*)d_in[0];
    const int*   nhi   = (const int*)d_in[1];
    const float* nhw   = (const float*)d_in[2];
    const int*   noi   = (const int*)d_in[3];
    const float* now_w = (const float*)d_in[4];
    const int*   bidx  = (const int*)d_in[5];
    const int*   dir   = (const int*)d_in[6];
    const int*   pt    = (const int*)d_in[7];
    const int*   rwid  = (const int*)d_in[8];
    const int*   roi   = (const int*)d_in[9];
    const float* row_w = (const float*)d_in[10];
    const float* xtv   = (const float*)d_in[11];
    const float* emb   = (const float*)d_in[12];
    const float* W0    = (const float*)d_in[13];
    const float* b0    = (const float*)d_in[14];
    const float* s0    = (const float*)d_in[15];
    const float* W1    = (const float*)d_in[16];
    const float* b1    = (const float*)d_in[17];
    const float* s1    = (const float*)d_in[18];
    const float* wcls  = (const float*)d_in[19];
    const float* wbias = (const float*)d_in[20];
    const float* ucls  = (const float*)d_in[21];
    const float* ubias = (const float*)d_in[22];

    float* ws   = (float*)d_ws;
    float* hbuf = ws;                                          // (E+1)*256
    float* W0T  = hbuf + (size_t)(E_ + 1) * H_;                // 65536
    float* W1T  = W0T + (size_t)H_ * H_;                       // 130816
    float* SC   = W1T + (size_t)(2 * H_ - 1) * H_;             // E*V
    float* part = SC + (size_t)E_ * V_;                        // 768*8
    ushort_t* Zb = (ushort_t*)(part + 768 * 8);                // E*KP bf16
    ushort_t* Wb = Zb + (size_t)E_ * KP;                       // VP*KP bf16
    float* out  = (float*)d_out;

    init_k<<<((E_ + 1) * H_ + 255) / 256, 256, 0, stream>>>(hbuf);
    transpose_k<<<(H_ * H_ + (2 * H_ - 1) * H_ + 255) / 256, 256, 0, stream>>>(W0, W1, W0T, W1T);
    wconv<<<(VP * KP + 255) / 256, 256, 0, stream>>>(wcls, Wb);

    {
        void* a0 = (void*)hbuf;  void* a1 = (void*)W0T;  void* a2 = (void*)b0;
        void* a3 = (void*)s0;    void* a4 = (void*)W1T;  void* a5 = (void*)b1;
        void* a6 = (void*)s1;    void* a7 = (void*)emb;  void* a8 = (void*)wid;
        void* a9 = (void*)nhi;   void* a10 = (void*)nhw;
        void* kargs[11] = {&a0, &a1, &a2, &a3, &a4, &a5, &a6, &a7, &a8, &a9, &a10};
        hipLaunchCooperativeKernel((const void*)scan_persist, dim3(M_), dim3(512),
                                   kargs, 0, stream);
    }

    zbuild2<<<E_, 256, 0, stream>>>(hbuf, xtv, bidx, Zb);
    gemm_mfma<<<dim3(E_ / 64, VP / 64), 256, 0, stream>>>(Zb, Wb, wbias, SC);
    msg_ce2<<<256, 256, 0, stream>>>(SC, pt, dir, part);
    stop_e2<<<256, 256, 0, stream>>>(hbuf, emb, xtv, wid, noi, now_w, bidx, dir, ucls, ubias, part);
    root_k<<<B_, 256, 0, stream>>>(hbuf, emb, xtv, rwid, roi, row_w, wcls, wbias, ucls, ubias, part);
    finalize2<<<1, 256, 0, stream>>>(part, out);
}

// Round 8
// 1087.832 us; speedup vs baseline: 2.4986x; 2.4986x over previous
//
#include <hip/hip_runtime.h>
#include <math.h>

#define T_ 64
#define M_ 256
#define K_ 6
#define B_ 256
#define H_ 256
#define L_ 128
#define V_ 780
#define E_ (T_*M_)       // 16384
#define ZD 383           // H+L-1
#define UD 638           // 2H+L-2
#define KP 384           // ZD padded for MFMA
#define VP 832           // V padded to 13*64

typedef unsigned short ushort_t;
typedef __attribute__((ext_vector_type(8))) _Float16 half8v;
typedef __attribute__((ext_vector_type(4))) _Float16 half4v;
typedef __attribute__((ext_vector_type(4))) float f32x4v;

// ---------------- helpers ----------------

__device__ __forceinline__ float blk_sum(float v, float* red) {
    int j = threadIdx.x;
    #pragma unroll
    for (int o = 32; o > 0; o >>= 1) v += __shfl_down(v, o, 64);
    __syncthreads();
    if ((j & 63) == 0) red[j >> 6] = v;
    __syncthreads();
    return red[0] + red[1] + red[2] + red[3];
}

__device__ __forceinline__ float wave_sum(float v) {
    #pragma unroll
    for (int o = 32; o > 0; o >>= 1) v += __shfl_xor(v, o, 64);
    return v;
}

__device__ __forceinline__ void wave_maxarg(float& v, int& i) {
    #pragma unroll
    for (int o = 32; o > 0; o >>= 1) {
        float vo = __shfl_xor(v, o, 64);
        int   io = __shfl_xor(i, o, 64);
        if (vo > v || (vo == v && io < i)) { v = vo; i = io; }
    }
}

// fp32 -> fp16 (RNE via HW convert)
__device__ __forceinline__ _Float16 f2h(float x) { return (_Float16)x; }

// ---------------- init ----------------

__global__ __launch_bounds__(256) void init_k(float* hbuf) {
    int idx = blockIdx.x * 256 + threadIdx.x;
    if (idx < (E_ + 1) * H_) hbuf[idx] = ((idx & (H_ - 1)) == 0) ? 1.f : 0.f;
}

// transpose + convert W0/W1 to fp16: W0H[i][j] = W0[j][i], W1H[i][j] = W1[j][i]
__global__ __launch_bounds__(256) void tconv(const float* __restrict__ W0,
                                             const float* __restrict__ W1,
                                             _Float16* __restrict__ W0H,
                                             _Float16* __restrict__ W1H) {
    int idx = blockIdx.x * 256 + threadIdx.x;
    if (idx < H_ * H_) {
        int i = idx >> 8, j = idx & 255;
        W0H[idx] = f2h(W0[j * H_ + i]);
    }
    int idx2 = idx - H_ * H_;
    if (idx2 >= 0 && idx2 < (2 * H_ - 1) * H_) {
        int i = idx2 >> 8, j = idx2 & 255;
        W1H[idx2] = f2h(W1[j * (2 * H_ - 1) + i]);
    }
}

// convert wcls -> fp16 padded [VP][KP]
__global__ __launch_bounds__(256) void wconv(const float* __restrict__ wcls,
                                             _Float16* __restrict__ Wh) {
    int idx = blockIdx.x * 256 + threadIdx.x;
    if (idx >= VP * KP) return;
    int v = idx / KP, k = idx - v * KP;
    float val = (v < V_ && k < ZD) ? wcls[(size_t)v * ZD + k] : 0.f;
    Wh[idx] = f2h(val);
}

// ---------------- sequential scan step: 512 threads (8 waves) per m ----------------
// 256 blocks (1 per m) x 8 waves (2/SIMD). Weights streamed from L2 as FP16
// (halved traffic vs fp32; fp16 has 10 mantissa bits -> 0.05% quantization,
// safe for the recurrence), converted to fp32 in-register, fp32 FMA.
// Reduction trees identical to the round-6 scan4 (passed).

__global__ __launch_bounds__(512) void scan4(int t, float* __restrict__ hbuf,
        const _Float16* __restrict__ W0H, const float* __restrict__ b0, const float* __restrict__ s0p,
        const _Float16* __restrict__ W1H, const float* __restrict__ b1, const float* __restrict__ s1p,
        const float* __restrict__ emb, const int* __restrict__ wid,
        const int* __restrict__ nhi, const float* __restrict__ nhw) {
    int tid = threadIdx.x;
    int w = tid >> 6, l = tid & 63;      // wave 0..7
    int j = tid & 255, half = tid >> 8;  // column, thread-half
    int m = blockIdx.x;

    __shared__ __align__(16) float hn[K_][H_];          // 6 KB
    __shared__ __align__(16) float pw0[8][K_][H_];      // 48 KB
    __shared__ __align__(16) float zz[512];             // 2 KB (511 used)
    __shared__ __align__(16) float py2[8][H_];          // 8 KB
    __shared__ __align__(16) float redk[4][8];
    __shared__ float y0s[K_];
    __shared__ float sca[1];

    const int*   ip = nhi + (t * M_ + m) * K_;
    const float* wp = nhw + (t * M_ + m) * K_;

    // stage neighbor rows: half 0 -> k 0..2, half 1 -> k 3..5
    #pragma unroll
    for (int k3 = 0; k3 < 3; k3++) {
        int k = half * 3 + k3;
        hn[k][j] = hbuf[(size_t)ip[k] * H_ + j];
    }
    __syncthreads();

    // ---- W0 GEMM: y[k][j] = sum_i hn[k][i] * W0[i][j]; wave w owns 32 i's ----
    float a0[K_][4];
    #pragma unroll
    for (int k = 0; k < K_; k++)
        #pragma unroll
        for (int c = 0; c < 4; c++) a0[k][c] = 0.f;
    {
        int i0 = w * 32;
        #pragma unroll 4
        for (int i = i0; i < i0 + 32; i++) {
            half4v hv = *(const half4v*)(W0H + (size_t)i * H_ + 4 * l);
            float wx = (float)hv[0], wy = (float)hv[1];
            float wzv = (float)hv[2], ww = (float)hv[3];
            #pragma unroll
            for (int k = 0; k < K_; k++) {
                float h = hn[k][i];
                a0[k][0] += h * wx; a0[k][1] += h * wy;
                a0[k][2] += h * wzv; a0[k][3] += h * ww;
            }
        }
    }
    #pragma unroll
    for (int k = 0; k < K_; k++)
        *(float4*)&pw0[w][k][4 * l] = make_float4(a0[k][0], a0[k][1], a0[k][2], a0[k][3]);
    __syncthreads();

    // reduce partials: thread owns col j (replicated across halves)
    float y[K_];
    float bj = b0[j];
    #pragma unroll
    for (int k = 0; k < K_; k++) {
        float s = pw0[0][k][j];
        #pragma unroll
        for (int ww2 = 1; ww2 < 8; ww2++) s += pw0[ww2][k][j];
        y[k] = s + bj;
    }

    // batched ssq reductions over j (waves 0..3 only)
    if (tid < 256) {
        int w4 = tid >> 6;
        #pragma unroll
        for (int k = 0; k < K_; k++) {
            float c = (tid == 0) ? 0.f : y[k] * y[k];
            c = wave_sum(c);
            if (l == 0) redk[w4][k] = c;
        }
        if (tid == 0) {
            #pragma unroll
            for (int k = 0; k < K_; k++) y0s[k] = y[k];
        }
    }
    __syncthreads();

    float es0 = expf(s0p[0]);
    float ave = 0.f, wsum = 0.f;
    #pragma unroll
    for (int k = 0; k < K_; k++) {
        float ssq = redk[0][k] + redk[1][k] + redk[2][k] + redk[3][k];
        float tm  = es0 / (1.f + expf(-y0s[k])) + 1.1f;
        float sc  = sqrtf((tm * tm - 1.f) / fmaxf(ssq, 1e-8f));
        float h1v = (j == 0) ? tm : y[k] * sc;
        float wk  = wp[k];
        ave += wk * h1v; wsum += wk;
    }
    ave /= fmaxf(wsum, 1e-8f);

    if (tid < 256) {
        int w4 = tid >> 6;
        float innl = (tid == 0) ? -ave * ave : ave * ave;
        innl = wave_sum(innl);
        if (l == 0) redk[w4][6] = innl;
    }
    __syncthreads();
    float inner = redk[0][6] + redk[1][6] + redk[2][6] + redk[3][6];
    float h1m = ave / sqrtf(fmaxf(-inner, 1e-8f));

    if (tid < 256) {
        int wde = wid[t * M_ + m];
        float cx = emb[(size_t)wde * H_ + j];
        if (j == 0) {
            zz[0] = sqrtf(fmaxf(cx * cx + h1m * h1m - 1.f, 1e-8f));
        } else {
            zz[j] = cx;
            zz[255 + j] = h1m;
        }
    }
    __syncthreads();

    // ---- W1 GEMM: y2[j] = sum_i zz[i] * W1[i][j]; wave w owns 64 i's ----
    float a1[4] = {0.f, 0.f, 0.f, 0.f};
    {
        int i0 = w * 64;
        int i1 = (i0 + 64 < 2 * H_ - 1) ? (i0 + 64) : (2 * H_ - 1);
        #pragma unroll 4
        for (int i = i0; i < i1; i++) {
            half4v hv = *(const half4v*)(W1H + (size_t)i * H_ + 4 * l);
            float z = zz[i];
            a1[0] += z * (float)hv[0]; a1[1] += z * (float)hv[1];
            a1[2] += z * (float)hv[2]; a1[3] += z * (float)hv[3];
        }
    }
    *(float4*)&py2[w][4 * l] = make_float4(a1[0], a1[1], a1[2], a1[3]);
    __syncthreads();

    if (tid < 256) {
        int w4 = tid >> 6;
        float y2 = py2[0][j];
        #pragma unroll
        for (int ww2 = 1; ww2 < 8; ww2++) y2 += py2[ww2][j];
        y2 += b1[j];
        float c2 = (tid == 0) ? 0.f : y2 * y2;
        c2 = wave_sum(c2);
        if (l == 0) redk[w4][7] = c2;
        if (tid == 0) sca[0] = y2;
        __syncthreads();
        float ssq2 = redk[0][7] + redk[1][7] + redk[2][7] + redk[3][7];
        float es1  = expf(s1p[0]);
        float tm2  = es1 / (1.f + expf(-sca[0])) + 1.1f;
        float sc2  = sqrtf((tm2 * tm2 - 1.f) / fmaxf(ssq2, 1e-8f));
        float nh   = (tid == 0) ? tm2 : y2 * sc2;
        hbuf[(size_t)(t * M_ + m) * H_ + j] = nh;
    } else {
        __syncthreads();   // matched barrier
    }
}

// ---------------- build Zh (fp16, K padded) with sign-folded z0 ----------------

__global__ __launch_bounds__(256) void zbuild2(const float* __restrict__ hbuf,
                                               const float* __restrict__ xtv,
                                               const int* __restrict__ bidx,
                                               _Float16* __restrict__ Zh) {
    int e = blockIdx.x, j = threadIdx.x;
    int bi = bidx[e];
    _Float16* zr = Zh + (size_t)e * KP;
    if (j == 0) {
        float nh0 = hbuf[(size_t)e * H_];
        float c0  = xtv[(size_t)bi * L_];
        float z0  = sqrtf(fmaxf(nh0 * nh0 + c0 * c0 - 1.f, 1e-8f));
        zr[0] = f2h(-z0);   // fold the centroid's -x0*cls0 sign here
    } else {
        zr[j] = f2h(hbuf[(size_t)e * H_ + j]);
    }
    if (j < 128) {
        int c = 256 + j;                       // 256..383
        float v = (c <= 382) ? xtv[(size_t)bi * L_ + (c - 255)] : 0.f;
        zr[c] = f2h(v);
    }
}

// ---------------- msg scores GEMM (MFMA fp16): SC = 2 + 2*(Z @ wcls^T) + wbias ----------------

__global__ __launch_bounds__(256) void gemm_mfma(const _Float16* __restrict__ Zh,
                                                 const _Float16* __restrict__ Wh,
                                                 const float* __restrict__ wbias,
                                                 float* __restrict__ SC) {
    __shared__ __align__(16) _Float16 As[64][40];
    __shared__ __align__(16) _Float16 Bs[64][40];
    int tid = threadIdx.x;
    int w = tid >> 6, l = tid & 63;
    int m0 = blockIdx.x * 64;
    int n0 = blockIdx.y * 64;
    int r16 = l & 15, q8 = (l >> 4) * 8;

    int srow = tid >> 2;            // 0..63
    int schunk = (tid & 3) * 8;     // 0,8,16,24

    f32x4v acc[4];
    #pragma unroll
    for (int mt = 0; mt < 4; mt++) acc[mt] = (f32x4v){0.f, 0.f, 0.f, 0.f};

    for (int ks = 0; ks < KP / 32; ks++) {
        int k0 = ks * 32;
        __syncthreads();
        *(uint4*)&As[srow][schunk] = *(const uint4*)(Zh + (size_t)(m0 + srow) * KP + k0 + schunk);
        *(uint4*)&Bs[srow][schunk] = *(const uint4*)(Wh + (size_t)(n0 + srow) * KP + k0 + schunk);
        __syncthreads();

        half8v bfr = *(const half8v*)(&Bs[w * 16 + r16][q8]);
        #pragma unroll
        for (int mt = 0; mt < 4; mt++) {
            half8v afr = *(const half8v*)(&As[mt * 16 + r16][q8]);
            acc[mt] = __builtin_amdgcn_mfma_f32_16x16x32_f16(afr, bfr, acc[mt], 0, 0, 0);
        }
    }

    int n = n0 + w * 16 + r16;
    if (n < V_) {
        float bias = wbias[n];
        #pragma unroll
        for (int mt = 0; mt < 4; mt++) {
            #pragma unroll
            for (int r = 0; r < 4; r++) {
                int mrow = m0 + mt * 16 + (l >> 4) * 4 + r;
                SC[(size_t)mrow * V_ + n] = 2.f + 2.f * acc[mt][r] + bias;
            }
        }
    }
}

// ---------------- msg CE (masked by direction), wave-per-row, no atomics ----------------

__global__ __launch_bounds__(256) void msg_ce2(const float* __restrict__ SC,
                                               const int* __restrict__ pt,
                                               const int* __restrict__ dir,
                                               float* __restrict__ part) {
    int w = threadIdx.x >> 6, l = threadIdx.x & 63;
    int wg = blockIdx.x * 4 + w;     // 0..1023
    float lloss = 0.f, lhit = 0.f, lpm = 0.f;
    for (int i = 0; i < 16; i++) {
        int e = wg * 16 + i;
        const float* s = SC + (size_t)e * V_;
        float sv[13];
        float mx = -1e30f; int mi = 0;
        #pragma unroll
        for (int ii = 0; ii < 13; ii++) {
            int v = l + ii * 64;
            float x = (v < V_) ? s[v] : -1e30f;
            sv[ii] = x;
            if (x > mx) { mx = x; mi = v; }
        }
        wave_maxarg(mx, mi);
        float se = 0.f;
        #pragma unroll
        for (int ii = 0; ii < 13; ii++) se += expf(sv[ii] - mx);
        se = wave_sum(se);
        if (l == 0) {
            int tgt = pt[e];
            float lse = mx + logf(se);
            float pm = (float)dir[e];
            lloss += pm * (lse - s[tgt]);
            lhit  += pm * ((mi == tgt) ? 1.f : 0.f);
            lpm   += pm;
        }
    }
    __shared__ float red[4][3];
    if (l == 0) { red[w][0] = lloss; red[w][1] = lhit; red[w][2] = lpm; }
    __syncthreads();
    if (threadIdx.x == 0) {
        float* pr = part + (size_t)blockIdx.x * 8;
        pr[0] = red[0][0] + red[1][0] + red[2][0] + red[3][0];
        pr[1] = red[0][1] + red[1][1] + red[2][1] + red[3][1];
        pr[2] = red[0][2] + red[1][2] + red[2][2] + red[3][2];
        pr[3] = 0.f; pr[4] = 0.f;
    }
}

// ---------------- stop head per message, wave-per-row, no atomics ----------------

__global__ __launch_bounds__(256) void stop_e2(const float* __restrict__ hbuf,
        const float* __restrict__ emb, const float* __restrict__ xtv,
        const int* __restrict__ wid, const int* __restrict__ noi, const float* __restrict__ now_w,
        const int* __restrict__ bidx, const int* __restrict__ dir,
        const float* __restrict__ ucls, const float* __restrict__ ubias,
        float* __restrict__ part) {
    int w = threadIdx.x >> 6, l = threadIdx.x & 63;
    int wg = blockIdx.x * 4 + w;

    float ua0[4], ub0[4], ua1[4], ub1[4], uc0[2], uc1[2];
    #pragma unroll
    for (int s = 0; s < 4; s++) {
        int j = s * 64 + l;
        ua0[s] = ucls[j];        ub0[s] = ucls[255 + j];
        ua1[s] = ucls[UD + j];   ub1[s] = ucls[UD + 255 + j];
    }
    #pragma unroll
    for (int s = 0; s < 2; s++) {
        int j = s * 64 + l;
        uc0[s] = ucls[510 + j];  uc1[s] = ucls[UD + 510 + j];
    }
    float u00 = ucls[0], u10 = ucls[UD];
    float ubs0 = ubias[0], ubs1 = ubias[1];

    float lloss = 0.f, lhit = 0.f;
    for (int i = 0; i < 16; i++) {
        int e = wg * 16 + i;
        const int*   ip = noi + e * K_;
        const float* wp = now_w + e * K_;
        float ave[4] = {0.f, 0.f, 0.f, 0.f};
        float wsum = 0.f;
        #pragma unroll
        for (int k = 0; k < K_; k++) {
            int id = ip[k]; float wt = wp[k];
            wsum += wt;
            const float* hr = hbuf + (size_t)id * H_;
            #pragma unroll
            for (int s = 0; s < 4; s++) ave[s] += wt * hr[s * 64 + l];
        }
        float inv = 1.f / fmaxf(wsum, 1e-8f);
        float innl = 0.f;
        #pragma unroll
        for (int s = 0; s < 4; s++) { ave[s] *= inv; innl += ave[s] * ave[s]; }
        if (l == 0) innl -= 2.f * ave[0] * ave[0];
        float inner = wave_sum(innl);
        float cs = 1.f / sqrtf(fmaxf(-inner, 1e-8f));

        int we = wid[e], bi = bidx[e];
        const float* er = emb + (size_t)we * H_;
        const float* cr = xtv + (size_t)bi * L_;

        float p0 = 0.f, p1 = 0.f;
        #pragma unroll
        for (int s = 0; s < 4; s++) {
            float cx = er[s * 64 + l];
            float co = ave[s] * cs;
            if (s == 0 && l == 0) {
                float ctx0 = cr[0];
                float t1sq = fmaxf(cx * cx + co * co - 1.f, 1e-8f);
                float sh0 = sqrtf(fmaxf(t1sq + ctx0 * ctx0 - 1.f, 1e-8f));
                p0 += -sh0 * u00; p1 += -sh0 * u10;
            } else {
                p0 += cx * ua0[s] + co * ub0[s];
                p1 += cx * ua1[s] + co * ub1[s];
            }
            if (s < 2) {
                int j = s * 64 + l;
                if (j >= 1) {
                    float ctx = cr[j];
                    p0 += ctx * uc0[s]; p1 += ctx * uc1[s];
                }
            }
        }
        p0 = wave_sum(p0); p1 = wave_sum(p1);
        if (l == 0) {
            float sc0 = 2.f + 2.f * p0 + ubs0;
            float sc1 = 2.f + 2.f * p1 + ubs1;
            int tgt = dir[e];
            float m = fmaxf(sc0, sc1);
            float lse = m + logf(expf(sc0 - m) + expf(sc1 - m));
            lloss += lse - ((tgt == 0) ? sc0 : sc1);
            int am = (sc1 > sc0) ? 1 : 0;
            lhit += (am == tgt) ? 1.f : 0.f;
        }
    }
    __shared__ float red[4][2];
    if (l == 0) { red[w][0] = lloss; red[w][1] = lhit; }
    __syncthreads();
    if (threadIdx.x == 0) {
        float* pr = part + (size_t)(256 + blockIdx.x) * 8;
        pr[0] = 0.f; pr[1] = 0.f; pr[2] = 0.f;
        pr[3] = red[0][0] + red[1][0] + red[2][0] + red[3][0];
        pr[4] = red[0][1] + red[1][1] + red[2][1] + red[3][1];
    }
}

// ---------------- root: stop head + pred head ----------------

__global__ __launch_bounds__(256) void root_k(const float* __restrict__ hbuf,
        const float* __restrict__ emb, const float* __restrict__ xtv,
        const int* __restrict__ rwid, const int* __restrict__ roi, const float* __restrict__ row_w,
        const float* __restrict__ wcls, const float* __restrict__ wbias,
        const float* __restrict__ ucls, const float* __restrict__ ubias,
        float* __restrict__ part) {
    int b = blockIdx.x, j = threadIdx.x;
    __shared__ float red[256];
    __shared__ int   redi[256];
    __shared__ float shs[4];
    __shared__ float ctxs[L_];
    __shared__ float sc[V_];
    float* pr = part + (size_t)(512 + b) * 8;

    const int*   ip = roi + b * K_;
    const float* wp = row_w + b * K_;
    float ave = 0.f, wsum = 0.f;
    #pragma unroll
    for (int k = 0; k < K_; k++) {
        int id = ip[k]; float w = wp[k];
        ave += w * hbuf[(size_t)id * H_ + j];
        wsum += w;
    }
    ave /= fmaxf(wsum, 1e-8f);
    float inner = blk_sum((j == 0) ? -ave * ave : ave * ave, red);
    float ro = ave / sqrtf(fmaxf(-inner, 1e-8f));

    int   rw = rwid[b];
    float er = emb[(size_t)rw * H_ + j];
    float ctxj = (j < L_) ? xtv[(size_t)b * L_ + j] : 0.f;
    if (j == 0) { shs[0] = er; shs[1] = ro; shs[2] = ctxj; }
    if (j < L_) ctxs[j] = ctxj;
    __syncthreads();
    float t1sq = fmaxf(shs[0] * shs[0] + shs[1] * shs[1] - 1.f, 1e-8f);
    float sh0  = sqrtf(fmaxf(t1sq + shs[2] * shs[2] - 1.f, 1e-8f));

    float p0, p1;
    if (j >= 1) {
        p0 = er * ucls[j] + ro * ucls[255 + j];
        p1 = er * ucls[UD + j] + ro * ucls[UD + 255 + j];
        if (j < L_) { p0 += ctxj * ucls[510 + j]; p1 += ctxj * ucls[UD + 510 + j]; }
    } else {
        p0 = -sh0 * ucls[0];
        p1 = -sh0 * ucls[UD];
    }
    float s0 = 2.f + 2.f * blk_sum(p0, red) + ubias[0];
    float s1 = 2.f + 2.f * blk_sum(p1, red) + ubias[1];
    if (j == 0) {
        float m = fmaxf(s0, s1);
        float lse = m + logf(expf(s0 - m) + expf(s1 - m));
        int am = (s1 > s0) ? 1 : 0;
        pr[3] = lse - s0;
        pr[4] = (am == 0) ? 1.f : 0.f;
    }

    float c0 = shs[2];
    float z0 = sqrtf(fmaxf(c0 * c0, 1e-8f));
    __syncthreads();
    for (int v = j; v < V_; v += 256) {
        const float* wv = wcls + (size_t)v * ZD;
        float d = -z0 * wv[0];
        for (int i = 1; i < L_; i++) d += ctxs[i] * wv[255 + i];
        sc[v] = 2.f + 2.f * d + wbias[v];
    }
    __syncthreads();
    float mx = -1e30f; int mi = 0;
    for (int v = j; v < V_; v += 256) { float x = sc[v]; if (x > mx) { mx = x; mi = v; } }
    red[j] = mx; redi[j] = mi;
    __syncthreads();
    for (int o = 128; o > 0; o >>= 1) {
        if (j < o) {
            float xo = red[j + o]; int io = redi[j + o];
            if (xo > red[j] || (xo == red[j] && io < redi[j])) { red[j] = xo; redi[j] = io; }
        }
        __syncthreads();
    }
    float gm = red[0]; int ga = redi[0];
    __syncthreads();
    float se = 0.f;
    for (int v = j; v < V_; v += 256) se += expf(sc[v] - gm);
    red[j] = se;
    __syncthreads();
    for (int o = 128; o > 0; o >>= 1) { if (j < o) red[j] += red[j + o]; __syncthreads(); }
    if (j == 0) {
        float lse = gm + logf(red[0]);
        pr[0] = lse - sc[rw];
        pr[1] = (ga == rw) ? 1.f : 0.f;
        pr[2] = 0.f;
    }
}

// ---------------- finalize ----------------

__global__ __launch_bounds__(256) void finalize2(const float* __restrict__ part,
                                                 float* __restrict__ out) {
    int j = threadIdx.x;
    __shared__ float red[256][5];
    #pragma unroll
    for (int c = 0; c < 5; c++)
        red[j][c] = part[(size_t)j * 8 + c] + part[(size_t)(j + 256) * 8 + c]
                  + part[(size_t)(j + 512) * 8 + c];
    __syncthreads();
    for (int o = 128; o > 0; o >>= 1) {
        if (j < o) {
            #pragma unroll
            for (int c = 0; c < 5; c++) red[j][c] += red[j + o][c];
        }
        __syncthreads();
    }
    if (j == 0) {
        out[0] = red[0][0] / (float)B_;
        out[1] = red[0][3] / (float)B_;
        out[2] = red[0][1] / ((float)B_ + red[0][2]);
        out[3] = red[0][4] / (float)(E_ + B_);
    }
}

// ---------------- launch ----------------

extern "C" void kernel_launch(void* const* d_in, const int* in_sizes, int n_in,
                              void* d_out, int out_size, void* d_ws, size_t ws_size,
                              hipStream_t stream) {
    const int*   wid   = (const int*)d_in[0];
    const int*   nhi   = (const int*)d_in[1];
    const float* nhw   = (const float*)d_in[2];
    const int*   noi   = (const int*)d_in[3];
    const float* now_w = (const float*)d_in[4];
    const int*   bidx  = (const int*)d_in[5];
    const int*   dir   = (const int*)d_in[6];
    const int*   pt    = (const int*)d_in[7];
    const int*   rwid  = (const int*)d_in[8];
    const int*   roi   = (const int*)d_in[9];
    const float* row_w = (const float*)d_in[10];
    const float* xtv   = (const float*)d_in[11];
    const float* emb   = (const float*)d_in[12];
    const float* W0    = (const float*)d_in[13];
    const float* b0    = (const float*)d_in[14];
    const float* s0    = (const float*)d_in[15];
    const float* W1    = (const float*)d_in[16];
    const float* b1    = (const float*)d_in[17];
    const float* s1    = (const float*)d_in[18];
    const float* wcls  = (const float*)d_in[19];
    const float* wbias = (const float*)d_in[20];
    const float* ucls  = (const float*)d_in[21];
    const float* ubias = (const float*)d_in[22];

    float* ws   = (float*)d_ws;
    float* hbuf = ws;                                          // (E+1)*256 f32
    float* SC   = hbuf + (size_t)(E_ + 1) * H_;                // E*V f32
    float* part = SC + (size_t)E_ * V_;                        // 768*8 f32
    _Float16* W0H = (_Float16*)(part + 768 * 8);               // H*H fp16
    _Float16* W1H = W0H + (size_t)H_ * H_;                     // (2H-1)*H fp16
    _Float16* Zh  = W1H + (size_t)(2 * H_ - 1) * H_;           // E*KP fp16
    _Float16* Wh  = Zh + (size_t)E_ * KP;                      // VP*KP fp16
    float* out  = (float*)d_out;

    init_k<<<((E_ + 1) * H_ + 255) / 256, 256, 0, stream>>>(hbuf);
    tconv<<<(H_ * H_ + (2 * H_ - 1) * H_ + 255) / 256, 256, 0, stream>>>(W0, W1, W0H, W1H);
    wconv<<<(VP * KP + 255) / 256, 256, 0, stream>>>(wcls, Wh);

    for (int t = 0; t < T_; t++) {
        scan4<<<M_, 512, 0, stream>>>(t, hbuf, W0H, b0, s0, W1H, b1, s1,
                                      emb, wid, nhi, nhw);
    }

    zbuild2<<<E_, 256, 0, stream>>>(hbuf, xtv, bidx, Zh);
    gemm_mfma<<<dim3(E_ / 64, VP / 64), 256, 0, stream>>>(Zh, Wh, wbias, SC);
    msg_ce2<<<256, 256, 0, stream>>>(SC, pt, dir, part);
    stop_e2<<<256, 256, 0, stream>>>(hbuf, emb, xtv, wid, noi, now_w, bidx, dir, ucls, ubias, part);
    root_k<<<B_, 256, 0, stream>>>(hbuf, emb, xtv, rwid, roi, row_w, wcls, wbias, ucls, ubias, part);
    finalize2<<<1, 256, 0, stream>>>(part, out);
}